// Round 1
// 762.449 us; speedup vs baseline: 1.0385x; 1.0385x over previous
//
#include <hip/hip_runtime.h>
#include <math.h>

// StructNDeconv2D: depthwise conv_transpose2d(stride=2,pad=1,dil=1,K=3) of
// (cd*d), cd, ones with softplus'd weights, then pointwise normalize.
//
// Row-pair formulation: output rows oy0=2a (even) and oy1=2a+1 (odd) consume
// exactly the same two input rows {a, a+1}, so one thread produces BOTH,
// halving per-output loads and index math. Verified tap algebra (from the
// previous harness-passing kernel):
//   even oy=2a : taps (a,  ixA)*w[1][kxA] + (a,  ixB)*w[1][2]*oddx
//   odd  oy=2a+1: taps (a+1,ixA)*w[0][kxA] + (a+1,ixB)*w[0][2]*oddx
//                    + (a,  ixA)*w[2][kxA] + (a,  ixB)*w[2][2]*oddx
// with ixA=(ox+1)>>1, ixB=ox>>1, kxA = oddx?0:1. All in-bounds for
// ox in [0,510]; row a+1 clamped (results masked at store) for a=255.

constexpr int B_ = 8, C_ = 32, IH = 256, IW = 256, OH = 511, OW = 511;
constexpr unsigned TOTAL  = (unsigned)B_ * C_ * OH * OW;   // 66,846,976 outputs per tensor
constexpr unsigned TOTAL2 = (unsigned)B_ * C_ * IH * OW;   // 33,423,488 row-pair threads
constexpr float EPS = 1e-20f;

__global__ void softplus_k(const float* __restrict__ w, float* __restrict__ sw) {
    int i = blockIdx.x * blockDim.x + threadIdx.x;
    if (i < C_ * 9) {
        float x = w[i];
        sw[i] = (x > 0.f) ? (x + log1pf(expf(-x))) : log1pf(expf(x));
    }
}

__global__ __launch_bounds__(256) void deconv_k(
    const float* __restrict__ d, const float* __restrict__ cd,
    const float* __restrict__ sw, const float* __restrict__ bias,
    float* __restrict__ out) {
    unsigned idx = blockIdx.x * blockDim.x + threadIdx.x;
    if (idx >= TOTAL2) return;

    unsigned ox = idx % OW;
    unsigned t  = idx / OW;
    unsigned a  = t & (IH - 1);   // input row / output row-pair index
    unsigned bc = t >> 8;
    unsigned c  = bc & (C_ - 1);
    const float* __restrict__ swc = sw + c * 9;

    const bool oddx = ox & 1u;
    const unsigned ixA = (ox + 1) >> 1, ixB = ox >> 1;
    const int   kxA = oddx ? 0 : 1;
    const float mxB = oddx ? 1.f : 0.f;   // second-column tap active only for odd ox

    const unsigned rA = a;
    const unsigned rB = (a < IH - 1) ? a + 1 : a;   // clamped; masked at store
    const unsigned base = bc * (IH * IW);
    const unsigned oA = base + rA * IW;
    const unsigned oB = base + rB * IW;

    const float c00 = cd[oA + ixA], c01 = cd[oA + ixB];
    const float c10 = cd[oB + ixA], c11 = cd[oB + ixB];
    const float d00 = d[oA + ixA],  d01 = d[oA + ixB];
    const float d10 = d[oB + ixA],  d11 = d[oB + ixB];

    // ---- even output row oy0 = 2a (kernel row 1 on input row a) ----
    const float wEA = swc[3 + kxA];
    const float wEB = swc[5] * mxB;
    const float den0 = wEA * c00 + wEB * c01;
    const float nom0 = wEA * c00 * d00 + wEB * c01 * d01;
    const float cds0 = wEA + wEB;

    // ---- odd output row oy1 = 2a+1 (row 0 on input a+1, row 2 on input a) ----
    const float wOA = swc[kxA];
    const float wOB = swc[2] * mxB;
    const float wOC = swc[6 + kxA];
    const float wOD = swc[8] * mxB;
    const float den1 = wOA * c10 + wOB * c11 + wOC * c00 + wOD * c01;
    const float nom1 = wOA * c10 * d10 + wOB * c11 * d11 +
                       wOC * c00 * d00 + wOD * c01 * d01;
    const float cds1 = wOA + wOB + wOC + wOD;

    const float bcb = bias[c];
    const unsigned obase = bc * (unsigned)(OH * OW);
    const unsigned o0 = obase + (2u * a) * OW + ox;

    // v_rcp_f32: ~1e-7 rel err, far under the 1.6e-2 abs tolerance; saves the
    // ~10-instruction precise-divide sequence per output.
    out[o0]         = nom0 * __builtin_amdgcn_rcpf(den0 + EPS) + bcb;
    out[TOTAL + o0] = den0 * __builtin_amdgcn_rcpf(cds0 + EPS);
    if (a < IH - 1) {
        const unsigned o1 = o0 + OW;
        out[o1]         = nom1 * __builtin_amdgcn_rcpf(den1 + EPS) + bcb;
        out[TOTAL + o1] = den1 * __builtin_amdgcn_rcpf(cds1 + EPS);
    }
}

extern "C" void kernel_launch(void* const* d_in, const int* in_sizes, int n_in,
                              void* d_out, int out_size, void* d_ws, size_t ws_size,
                              hipStream_t stream) {
    const float* d    = (const float*)d_in[0];
    const float* cd   = (const float*)d_in[1];
    const float* w    = (const float*)d_in[2];
    const float* bias = (const float*)d_in[3];
    float* out = (float*)d_out;
    float* sw  = (float*)d_ws;  // 288 floats of softplus'd weights

    softplus_k<<<2, 256, 0, stream>>>(w, sw);
    const unsigned nblk = (TOTAL2 + 255u) / 256u;   // 130,560 blocks
    deconv_k<<<nblk, 256, 0, stream>>>(d, cd, sw, bias, out);
}